// Round 4
// baseline (314.390 us; speedup 1.0000x reference)
//
#include <hip/hip_runtime.h>
#include <math.h>

// Problem constants (fixed by setup_inputs)
#define BB 32
#define NN 1024
#define DD 1024
#define HH 512

// out layout (floats): [one_hot 32*1024*1024][masked_acts 32*1024][kl 32][log_nom 32][log_norm 32]
#define OUT0_OFF 0
#define OUT1_OFF (BB * NN * NN)
#define OUT2_OFF (OUT1_OFF + BB * NN)
#define OUT3_OFF (OUT2_OFF + BB)
#define OUT4_OFF (OUT3_OFF + BB)

// ws layout (bytes): acts fp32 [32768] @0 ; W1T bf16 [512][1024] @131072 ; rank int[32768] @1179648
#define WS_ACTS 0
#define WS_W1T  131072
#define WS_RANK 1179648

typedef __attribute__((ext_vector_type(8))) short short8;
typedef __attribute__((ext_vector_type(4))) float floatx4;

__device__ inline unsigned int f2bf(float x) {  // RNE fp32 -> bf16 bits
    unsigned int u = __builtin_bit_cast(unsigned int, x);
    return (u + 0x7FFFu + ((u >> 16) & 1u)) >> 16;
}

// async global->LDS DMA, 16 B per lane, LDS dest = wave-uniform base + lane*16
__device__ inline void gload_lds16(const void* g, void* l) {
    __builtin_amdgcn_global_load_lds(
        (const __attribute__((address_space(1))) unsigned int*)g,
        (__attribute__((address_space(3))) unsigned int*)l, 16, 0, 0);
}

// ---------------------------------------------------------------------------
// K0: transpose + convert W1 [d=1024][h=512] fp32 -> W1T [h=512][d=1024] bf16
// ---------------------------------------------------------------------------
__global__ __launch_bounds__(1024) void w1t_kernel(const float* __restrict__ W1,
                                                   unsigned short* __restrict__ W1T)
{
    __shared__ float T[32][33];
    const int tx = threadIdx.x, ty = threadIdx.y;
    const int d0 = blockIdx.x * 32, h0 = blockIdx.y * 32;
    T[ty][tx] = W1[(d0 + ty) * HH + h0 + tx];
    __syncthreads();
    W1T[(size_t)(h0 + ty) * DD + d0 + tx] = (unsigned short)f2bf(T[tx][ty]);
}

// ---------------------------------------------------------------------------
// K1: MFMA GEMM + fused relu/W2 epilogue.
// 256 threads (4 waves), M=64, N=512, K-step 32, grid 512 = 2 blocks/CU
// (round 3's M=128/1-block lost cross-block overlap (m114) — restored here).
// Per K-step (counted-vmcnt pipeline, T4 issue-before-wait, static parity):
//   { lgkmcnt(0); s_barrier;
//     issue 8 B-DMA(k+1) -> Bs[nxt];
//     s_waitcnt vmcnt(8)          // old iter's 8 DMA + 2 A-loads retired,
//                                 // the 8 just-issued stay IN FLIGHT
//     pack A(k+1) regs -> As[nxt]; issue A-loads(k+2);
//     ds_read + 32 MFMA on tile k }
// Loads issued in iter k have a full iteration before their drain in k+1,
// and the new DMAs' issue/latency hides UNDER the wait for the old ones.
// Buffer parity is compile-time (2x manual unroll) — no runtime LDS base
// arithmetic, no aliasing conservatism between in-flight DMAs and ds_reads.
// B staging: zero-VGPR global_load_lds; A staging: 8 VGPRs, depth 2.
// LDS rows 64 B linear, XOR swizzle byte[5:4] ^= ((row>>1)&3) on BOTH DMA
// source and frag reads (rule 21) -> measured 0 bank conflicts.
// LDS: 2*32K B + 2*4K A + 1K red = 73 KB -> 2 blocks/CU.  ~88 VGPR + 128 AGPR.
// ---------------------------------------------------------------------------
#define MT 64

#define GEMM_STAGE(kk, NXTBUF)                                                 \
    do {                                                                       \
        if ((kk) < 31) {                                                       \
            _Pragma("unroll")                                                  \
            for (int j = 0; j < 8; ++j)                                        \
                gload_lds16(w1tb + (boff[j] + ((kk) + 1) * 64),                \
                            (char*)(&Bs[NXTBUF][0]) + (w * 8 + j) * 1024);     \
            asm volatile("s_waitcnt vmcnt(8)" ::: "memory");                   \
            uint4 pk;                                                          \
            pk.x = f2bf(a0.x) | (f2bf(a0.y) << 16);                            \
            pk.y = f2bf(a0.z) | (f2bf(a0.w) << 16);                            \
            pk.z = f2bf(a1.x) | (f2bf(a1.y) << 16);                            \
            pk.w = f2bf(a1.z) | (f2bf(a1.w) << 16);                            \
            *(uint4*)((char*)(&As[NXTBUF][0]) + srow * 64 + asw) = pk;         \
            const int ka = ((kk) < 30) ? (kk) + 2 : 31;                        \
            const float4* ap = (const float4*)(aptr + ka * 32);                \
            a0 = ap[0]; a1 = ap[1];                                            \
        } else {                                                               \
            asm volatile("s_waitcnt vmcnt(0)" ::: "memory");                   \
        }                                                                      \
    } while (0)

#define GEMM_COMPUTE(CURBUF)                                                   \
    do {                                                                       \
        __builtin_amdgcn_s_setprio(1);                                         \
        short8 af[4];                                                          \
        _Pragma("unroll")                                                      \
        for (int tm = 0; tm < 4; ++tm)                                         \
            af[tm] = *(const short8*)((const char*)(&As[CURBUF][0]) + aoff[tm]);\
        _Pragma("unroll")                                                      \
        for (int tn = 0; tn < 8; ++tn) {                                       \
            short8 bf =                                                        \
                *(const short8*)((const char*)(&Bs[CURBUF][0]) + boffr[tn]);   \
            _Pragma("unroll")                                                  \
            for (int tm = 0; tm < 4; ++tm)                                     \
                acc[tn][tm] = __builtin_amdgcn_mfma_f32_16x16x32_bf16(         \
                    af[tm], bf, acc[tn][tm], 0, 0, 0);                         \
        }                                                                      \
        __builtin_amdgcn_s_setprio(0);                                         \
    } while (0)

#define GEMM_BODY(kk, CURBUF)                                                  \
    do {                                                                       \
        asm volatile("s_waitcnt lgkmcnt(0)" ::: "memory");                     \
        __builtin_amdgcn_s_barrier();                                          \
        GEMM_STAGE(kk, (CURBUF) ^ 1);                                          \
        GEMM_COMPUTE(CURBUF);                                                  \
    } while (0)

__global__ __launch_bounds__(256, 2) void gemm_acts_kernel(
    const float* __restrict__ q, const unsigned short* __restrict__ W1T,
    const float* __restrict__ b1, const float* __restrict__ W2,
    const float* __restrict__ b2, const float* __restrict__ unoise,
    float* __restrict__ acts_ws, float* __restrict__ out1)
{
    __shared__ short As[2][MT * 32];   // 2 x 4096 B, swizzled 64 B rows
    __shared__ short Bs[2][HH * 32];   // 2 x 32768 B, swizzled 64 B rows
    __shared__ float red[MT][4];

    const int tid  = threadIdx.x;
    const int w    = tid >> 6;         // wave 0..3
    const int lane = tid & 63;
    const int c    = lane & 15;        // fragment row/col-in-tile
    const int qd   = lane >> 4;        // quad 0..3
    const int m0   = blockIdx.x * MT;

    floatx4 acc[8][4];
    #pragma unroll
    for (int tn = 0; tn < 8; ++tn)
        #pragma unroll
        for (int tm = 0; tm < 4; ++tm)
            acc[tn][tm] = (floatx4){0.f, 0.f, 0.f, 0.f};

    // B DMA: 32 chunks of 1 KB (16 rows x 64 B); wave w stages chunks w*8+j.
    // Lane covers row n = chunk*16 + (lane>>2), stored col c0 = (lane&3)*16.
    // Stored col c0 holds element bytes c0 ^ (s<<4), s = (n>>1)&3 (involution),
    // so pre-swizzle the SOURCE address (m173 pattern).
    int boff[8];
    #pragma unroll
    for (int j = 0; j < 8; ++j) {
        int n  = (w * 8 + j) * 16 + (lane >> 2);
        int c0 = (lane & 3) * 16;
        int s  = (n >> 1) & 3;
        boff[j] = n * 2048 + (c0 ^ (s << 4));
    }
    const char* w1tb = (const char*)W1T;

    // A staging: thread -> row srow=tid/4 (0..63), 8 floats at (tid%4)*8
    const int srow = tid >> 2, skp = tid & 3;
    const float* aptr = q + (size_t)(m0 + srow) * DD + skp * 8;
    const int asw = (skp * 16) ^ (((srow >> 1) & 3) << 4);  // swizzled byte col

    // loop-invariant frag-read byte offsets (same XOR on the read side)
    int aoff[4], boffr[8];
    #pragma unroll
    for (int tm = 0; tm < 4; ++tm) {
        int r = tm * 16 + c;
        aoff[tm] = r * 64 + ((qd * 16) ^ (((r >> 1) & 3) << 4));
    }
    #pragma unroll
    for (int tn = 0; tn < 8; ++tn) {
        int n = w * 128 + tn * 16 + c;
        boffr[tn] = n * 64 + ((qd * 16) ^ (((n >> 1) & 3) << 4));
    }

    float4 a0, a1;

    // ---- prologue: issue B DMA(0) -> Bs[0]; pack A(0) -> As[0] (sync);
    //      issue A-loads(1) into regs.  vm outstanding entering loop = 10. ----
    #pragma unroll
    for (int j = 0; j < 8; ++j)
        gload_lds16(w1tb + boff[j], (char*)(&Bs[0][0]) + (w * 8 + j) * 1024);
    {
        const float4* ap = (const float4*)aptr;
        float4 v0 = ap[0], v1 = ap[1];
        uint4 pk;
        pk.x = f2bf(v0.x) | (f2bf(v0.y) << 16);
        pk.y = f2bf(v0.z) | (f2bf(v0.w) << 16);
        pk.z = f2bf(v1.x) | (f2bf(v1.y) << 16);
        pk.w = f2bf(v1.z) | (f2bf(v1.w) << 16);
        *(uint4*)((char*)(&As[0][0]) + srow * 64 + asw) = pk;
        const float4* ap1 = (const float4*)(aptr + 32);
        a0 = ap1[0]; a1 = ap1[1];
    }

    #pragma unroll 1
    for (int ku = 0; ku < 16; ++ku) {
        GEMM_BODY(ku * 2,     0);
        GEMM_BODY(ku * 2 + 1, 1);
    }

    // epilogue: h = relu(acc + b1); rowsum += h*W2; reduce 16 cols + 4 waves
    float b1v[8], w2v[8];
    #pragma unroll
    for (int tn = 0; tn < 8; ++tn) {
        int col = w * 128 + tn * 16 + c;
        b1v[tn] = b1[col];
        w2v[tn] = W2[col];
    }
    #pragma unroll
    for (int tm = 0; tm < 4; ++tm) {
        #pragma unroll
        for (int r = 0; r < 4; ++r) {
            float p = 0.f;
            #pragma unroll
            for (int tn = 0; tn < 8; ++tn) {
                float v = acc[tn][tm][r] + b1v[tn];
                p = fmaf(fmaxf(v, 0.f), w2v[tn], p);
            }
            p += __shfl_xor(p, 1);
            p += __shfl_xor(p, 2);
            p += __shfl_xor(p, 4);
            p += __shfl_xor(p, 8);
            if (c == 0) red[tm * 16 + qd * 4 + r][w] = p;
        }
    }
    __syncthreads();
    if (tid < MT) {
        float raw = red[tid][0] + red[tid][1] + red[tid][2] + red[tid][3] + b2[0];
        float sp = fmaxf(raw, 0.f) + log1pf(expf(-fabsf(raw)));  // stable softplus
        int row = m0 + tid;
        float av = logf(fmaxf(sp, 1e-5f)) + unoise[row];
        acts_ws[row] = av;
        out1[row]    = av;
    }
}

// ---------------------------------------------------------------------------
// K2: zero the one-hot output region
// ---------------------------------------------------------------------------
__global__ __launch_bounds__(256) void zero_kernel(float4* __restrict__ p, int n4)
{
    int idx = blockIdx.x * blockDim.x + threadIdx.x;
    int stride = gridDim.x * blockDim.x;
    float4 z = make_float4(0.f, 0.f, 0.f, 0.f);
    for (int i = idx; i < n4; i += stride) p[i] = z;
}

// ---------------------------------------------------------------------------
// K3: rank-by-counting, spread across 128 blocks (4 per batch, 256 i each)
// ---------------------------------------------------------------------------
__global__ __launch_bounds__(256) void rank_kernel(
    const float* __restrict__ acts_ws, const float* __restrict__ gumbel,
    int* __restrict__ rank)
{
    __shared__ float P[NN];
    const int b = blockIdx.x >> 2;
    const int chunk = blockIdx.x & 3;
    const int tid = threadIdx.x;
    #pragma unroll
    for (int r = 0; r < 4; ++r) {
        int j = r * 256 + tid;
        P[j] = acts_ws[b * NN + j] + gumbel[b * NN + j];
    }
    __syncthreads();
    const int i = chunk * 256 + tid;
    const float pert = P[i];
    int cnt = 0;
    const float4* P4 = (const float4*)P;
    for (int j4 = 0; j4 < NN / 4; ++j4) {
        float4 pv = P4[j4];  // broadcast
        int j = j4 * 4;
        cnt += (pv.x > pert) || (pv.x == pert && j + 0 < i);
        cnt += (pv.y > pert) || (pv.y == pert && j + 1 < i);
        cnt += (pv.z > pert) || (pv.z == pert && j + 2 < i);
        cnt += (pv.w > pert) || (pv.w == pert && j + 3 < i);
    }
    rank[b * NN + i] = cnt;
}

// ---------------------------------------------------------------------------
// K4: per-batch permutation, one-hot scatter, PL likelihood, kl.
// Wave-level shfl suffix-scan + butterfly reductions: 4 block barriers total.
// ---------------------------------------------------------------------------
__global__ __launch_bounds__(1024) void permu_stats_kernel(
    const float* __restrict__ acts_ws, const int* __restrict__ rank,
    float* __restrict__ out0, float* __restrict__ out2,
    float* __restrict__ out3, float* __restrict__ out4)
{
    __shared__ float A[NN];
    __shared__ int   IDX[NN];
    __shared__ float WT[16];
    __shared__ float WSUF[17];
    __shared__ float P0[16], P1[16], P2[16];

    const int b = blockIdx.x;
    const int i = threadIdx.x;
    const int lane = i & 63;
    const int w = i >> 6;            // wave 0..15

    float a = acts_ws[b * NN + i];
    A[i] = a;
    IDX[rank[b * NN + i]] = i;
    __syncthreads();                                        // barrier A

    int perm = (i == 0) ? 0 : IDX[i - 1];
    out0[((size_t)b * NN + i) * NN + perm] = 1.0f;

    float e = expf(A[perm]);
    // intra-wave inclusive suffix sum of e
    float s = e;
    #pragma unroll
    for (int off = 1; off < 64; off <<= 1) {
        float v = __shfl_down(s, off);
        if (lane + off < 64) s += v;
    }
    if (lane == 0) WT[w] = s;        // wave total (suffix from lane 0)
    __syncthreads();                                        // barrier B
    if (w == 0) {
        float t = (lane < 16) ? WT[lane] : 0.f;
        #pragma unroll
        for (int off = 1; off < 16; off <<= 1) {
            float v = __shfl_down(t, off);
            if (lane + off < 16) t += v;
        }
        if (lane < 16) WSUF[lane] = t;   // sum over waves >= lane
        if (lane == 0) WSUF[16] = 0.f;
    }
    __syncthreads();                                        // barrier C

    float S = s + WSUF[w + 1];       // full suffix sum_{j>=i} e_j
    float term = logf(e + 1e-20f) - logf(S + 1e-20f);

    // three simultaneous full-wave butterfly reductions
    float r0 = term, r1 = a, r2 = expf(-fmaxf(a, -20.f));
    #pragma unroll
    for (int off = 1; off < 64; off <<= 1) {
        r0 += __shfl_xor(r0, off);
        r1 += __shfl_xor(r1, off);
        r2 += __shfl_xor(r2, off);
    }
    if (lane == 0) { P0[w] = r0; P1[w] = r1; P2[w] = r2; }
    __syncthreads();                                        // barrier D
    if (i == 0) {
        float t0 = 0.f, t1 = 0.f, t2 = 0.f;
        #pragma unroll
        for (int k = 0; k < 16; ++k) { t0 += P0[k]; t1 += P1[k]; t2 += P2[k]; }
        out3[b] = t0;
        out2[b] = -(float)NN + t1 + t2;
        out4[b] = 0.f;
    }
}

extern "C" void kernel_launch(void* const* d_in, const int* in_sizes, int n_in,
                              void* d_out, int out_size, void* d_ws, size_t ws_size,
                              hipStream_t stream)
{
    const float* q      = (const float*)d_in[0];
    const float* W1     = (const float*)d_in[2];
    const float* b1     = (const float*)d_in[3];
    const float* W2     = (const float*)d_in[4];
    const float* b2     = (const float*)d_in[5];
    const float* unoise = (const float*)d_in[6];
    const float* gumbel = (const float*)d_in[7];

    float* out  = (float*)d_out;
    char*  ws   = (char*)d_ws;
    float*          acts = (float*)(ws + WS_ACTS);
    unsigned short* W1T  = (unsigned short*)(ws + WS_W1T);
    int*            rank = (int*)(ws + WS_RANK);

    w1t_kernel<<<dim3(32, 16), dim3(32, 32), 0, stream>>>(W1, W1T);
    gemm_acts_kernel<<<(BB * NN) / MT, 256, 0, stream>>>(q, W1T, b1, W2, b2,
                                                         unoise, acts,
                                                         out + OUT1_OFF);
    zero_kernel<<<8192, 256, 0, stream>>>((float4*)(out + OUT0_OFF),
                                          (BB * NN * NN) / 4);
    rank_kernel<<<BB * 4, 256, 0, stream>>>(acts, gumbel, rank);
    permu_stats_kernel<<<BB, 1024, 0, stream>>>(acts, rank,
                                                out + OUT0_OFF, out + OUT2_OFF,
                                                out + OUT3_OFF, out + OUT4_OFF);
}